// Round 1
// 971.351 us; speedup vs baseline: 1.0849x; 1.0849x over previous
//
#include <hip/hip_runtime.h>
#include <hip/hip_bf16.h>
#include <cstdint>
#include <cstddef>

#define D_MODEL 768
#define D_INNER 1536
#define DT_RANK 48
#define D_STATE 16
#define SEQ     1024
#define BATCH   2
#define NROWS   2048      // BATCH*SEQ
#define VOCAB   32000
#define LCHUNK  16
#define NCHUNK  64        // SEQ / LCHUNK
#define CHST    49152     // 3072 channels * 16 states

typedef __hip_bfloat16 bf16;
typedef short bf16x8 __attribute__((ext_vector_type(8)));   // 8 bf16 in 4 VGPRs
typedef float f32x4  __attribute__((ext_vector_type(4)));
struct bf8 { bf16 v[8]; };

// ---------------------------------------------------------------------------
// async global->LDS, 16B per lane. LDS dest = wave-uniform base + lane*16.
__device__ __forceinline__ void async_copy16(void* lds, const void* gp) {
    __builtin_amdgcn_global_load_lds(
        (const __attribute__((address_space(1))) unsigned int*)gp,
        (__attribute__((address_space(3)))       unsigned int*)lds,
        16, 0, 0);
}

// ===========================================================================
// gemm256: 256x256 tile, BK=64, 8 waves (2Mx4N), 128 KiB LDS double buffer,
// 8-phase schedule with counted vmcnt (T3+T4), XOR chunk swizzle (T2, applied
// as linear LDS dest + inverse-swizzled GLOBAL source + swizzled ds_read),
// setprio around MFMA (T5), bijective XCD blockIdx swizzle (T1).
// Requirements: M%256==0, N%256==0, K%128==0, grid = (M/256)*(N/256) % 8 == 0.
// C = A(M,K) * B(N,K)^T, bf16 in / f32 out.
// ===========================================================================

#define LDSP(BUF, AB) (smem + (((BUF)*2 + (AB)) << 15))

#define PHB() do { \
  __builtin_amdgcn_sched_barrier(0); \
  __builtin_amdgcn_s_barrier(); \
  __builtin_amdgcn_sched_barrier(0); \
} while (0)

#define WAIT_VMCNT(n) do { \
  asm volatile("s_waitcnt vmcnt(" #n ")" ::: "memory"); \
  __builtin_amdgcn_sched_barrier(0); \
} while (0)

// stage one A half-tile (regions rows {h*64..h*64+64} U {128+h*64..}) of
// K-tile KT into buffer BUF. 2 x global_load_lds per thread (8KB each / block).
#define STAGE_A(BUF, H, KT) do { \
  const int ru0_ = (H)*64 + wave*8; \
  const int ru1_ = ru0_ + 128; \
  const bf16* ga0_ = Ag + (size_t)(m0 + ru0_ + (lane >> 3)) * (size_t)K + (size_t)((KT)*64 + swz8); \
  const bf16* ga1_ = Ag + (size_t)(m0 + ru1_ + (lane >> 3)) * (size_t)K + (size_t)((KT)*64 + swz8); \
  async_copy16(LDSP(BUF, 0) + ru0_*128, ga0_); \
  async_copy16(LDSP(BUF, 0) + ru1_*128, ga1_); \
} while (0)

// stage one B half-tile (rows {q*64 + h*32 + [0,32)}, q=0..3) of K-tile KT.
#define STAGE_B(BUF, H, KT) do { \
  const int lb0_ = wave*8, lb1_ = 64 + wave*8; \
  const int rb0_ = ((lb0_ >> 5) << 6) + (H)*32 + (lb0_ & 31); \
  const int rb1_ = ((lb1_ >> 5) << 6) + (H)*32 + (lb1_ & 31); \
  const bf16* gb0_ = Bg + (size_t)(n0 + rb0_ + (lane >> 3)) * (size_t)K + (size_t)((KT)*64 + swz8); \
  const bf16* gb1_ = Bg + (size_t)(n0 + rb1_ + (lane >> 3)) * (size_t)K + (size_t)((KT)*64 + swz8); \
  async_copy16(LDSP(BUF, 1) + rb0_*128, gb0_); \
  async_copy16(LDSP(BUF, 1) + rb1_*128, gb1_); \
} while (0)

// LDS[row][chunk16B] holds global col-block (chunk ^ (row&7)); reads XOR back.
#define RDA4(BUF, MH) do { \
  _Pragma("unroll") \
  for (int i2_ = 0; i2_ < 4; ++i2_) { \
    const char* rp_ = LDSP(BUF, 0) + (wr*128 + (MH)*64 + i2_*16 + fm) * 128; \
    a[i2_][0] = *(const bf16x8*)(rp_ + (((kqi    ) ^ fm7) << 4)); \
    a[i2_][1] = *(const bf16x8*)(rp_ + (((4 + kqi) ^ fm7) << 4)); \
  } \
} while (0)

#define RDB4(BUF, NH, DST) do { \
  _Pragma("unroll") \
  for (int j2_ = 0; j2_ < 2; ++j2_) { \
    const char* rp_ = LDSP(BUF, 1) + (wc*64 + (NH)*32 + j2_*16 + fm) * 128; \
    DST[j2_][0] = *(const bf16x8*)(rp_ + (((kqi    ) ^ fm7) << 4)); \
    DST[j2_][1] = *(const bf16x8*)(rp_ + (((4 + kqi) ^ fm7) << 4)); \
  } \
} while (0)

#define QMFMA(MH, NH, BB) do { \
  __builtin_amdgcn_s_setprio(1); \
  _Pragma("unroll") \
  for (int i2_ = 0; i2_ < 4; ++i2_) { \
    _Pragma("unroll") \
    for (int j2_ = 0; j2_ < 2; ++j2_) { \
      acc[(MH)*4 + i2_][(NH)*2 + j2_] = __builtin_amdgcn_mfma_f32_16x16x32_bf16( \
          a[i2_][0], BB[j2_][0], acc[(MH)*4 + i2_][(NH)*2 + j2_], 0, 0, 0); \
      acc[(MH)*4 + i2_][(NH)*2 + j2_] = __builtin_amdgcn_mfma_f32_16x16x32_bf16( \
          a[i2_][1], BB[j2_][1], acc[(MH)*4 + i2_][(NH)*2 + j2_], 0, 0, 0); \
    } \
  } \
  __builtin_amdgcn_s_setprio(0); \
} while (0)

// 8 phases = 2 K-tiles (tt in buf0, tt+1 in buf1). Each phase stages exactly
// one half-tile; a region is staged only >=1 phase after its last LDS read.
// vmcnt(6) at phases 4/8 = 3 half-tiles in flight (never drain to 0 mid-loop).
#define ITER(TT, LAST) do { \
  RDA4(0, 0); RDB4(0, 0, b0); \
  STAGE_B(1, 1, (TT) + 1); \
  PHB(); QMFMA(0, 0, b0); PHB(); \
  RDB4(0, 1, b1); \
  if (!(LAST)) STAGE_A(0, 0, (TT) + 2); \
  PHB(); QMFMA(0, 1, b1); PHB(); \
  RDA4(0, 1); \
  if (!(LAST)) STAGE_B(0, 0, (TT) + 2); \
  PHB(); QMFMA(1, 0, b0); PHB(); \
  if (!(LAST)) { STAGE_A(0, 1, (TT) + 2); WAIT_VMCNT(6); } else { WAIT_VMCNT(0); } \
  PHB(); QMFMA(1, 1, b1); PHB(); \
  RDA4(1, 0); RDB4(1, 0, b0); \
  if (!(LAST)) STAGE_B(0, 1, (TT) + 2); \
  PHB(); QMFMA(0, 0, b0); PHB(); \
  RDB4(1, 1, b1); \
  if (!(LAST)) STAGE_A(1, 0, (TT) + 3); \
  PHB(); QMFMA(0, 1, b1); PHB(); \
  RDA4(1, 1); \
  if (!(LAST)) STAGE_B(1, 0, (TT) + 3); \
  PHB(); QMFMA(1, 0, b0); PHB(); \
  if (!(LAST)) { STAGE_A(1, 1, (TT) + 3); WAIT_VMCNT(6); } else { WAIT_VMCNT(0); } \
  PHB(); QMFMA(1, 1, b1); PHB(); \
} while (0)

__global__ __launch_bounds__(512, 2) void gemm256(
    const bf16* __restrict__ Ag, const bf16* __restrict__ Bg,
    float* __restrict__ C, int M, int N, int K, int ntm)
{
    (void)M;
    __shared__ __align__(16) char smem[131072];   // [buf][A/B] 4 x 32KB

    // bijective XCD swizzle: grid % 8 == 0 guaranteed by caller
    const int cpx  = gridDim.x >> 3;
    const int bid  = blockIdx.x;
    const int wgid = (bid & 7) * cpx + (bid >> 3);
    const int m0 = (wgid % ntm) << 8;
    const int n0 = (wgid / ntm) << 8;

    const int t    = threadIdx.x;
    const int wave = t >> 6, lane = t & 63;
    const int wr = wave >> 2, wc = wave & 3;     // 2 x 4 wave grid
    const int fm  = lane & 15, fm7 = lane & 7;
    const int kqi = lane >> 4;
    // inverse-swizzled global source column (elements): chunk^(row&7), row&7=(lane>>3)
    const int swz8 = (((lane & 7) ^ ((lane >> 3) & 7)) << 3);
    const int nkt = K >> 6;

    f32x4 acc[8][4];
    #pragma unroll
    for (int i = 0; i < 8; ++i)
        #pragma unroll
        for (int j = 0; j < 4; ++j)
            acc[i][j] = {0.f, 0.f, 0.f, 0.f};

    bf16x8 a[4][2], b0[2][2], b1[2][2];

    // prologue: tile 0 -> buf0 (4 halves), tile 1 -> buf1 (3 of 4 halves)
    STAGE_A(0, 0, 0); STAGE_A(0, 1, 0); STAGE_B(0, 0, 0); STAGE_B(0, 1, 0);
    WAIT_VMCNT(4);
    STAGE_A(1, 0, 1); STAGE_A(1, 1, 1); STAGE_B(1, 0, 1);
    WAIT_VMCNT(6);          // tile 0 fully landed (this wave)
    PHB();                  // all waves' tile-0 loads landed

    int tt = 0;
    #pragma unroll 1
    for (; tt + 2 < nkt; tt += 2) { ITER(tt, false); }
    ITER(tt, true);

    // C/D layout: col = lane&15, row = (lane>>4)*4 + reg
    const int lr = (lane >> 4) * 4;
    const int lc = lane & 15;
    #pragma unroll
    for (int i = 0; i < 8; ++i) {
        #pragma unroll
        for (int j = 0; j < 4; ++j) {
            const size_t base = (size_t)(m0 + wr*128 + i*16 + lr) * N
                              + (size_t)(n0 + wc*64 + j*16 + lc);
            #pragma unroll
            for (int r = 0; r < 4; ++r)
                C[base + (size_t)r * N] = acc[i][j][r];
        }
    }
}

// ---------------------------------------------------------------------------
// GEMM: C(M,N) = A(M,K) * B(N,K)^T.  A,B bf16 row-major (lda = leading dim),
// K = depth this launch processes.  blockIdx.y = split-K slice: reads cols
// [z*K, (z+1)*K), writes partial to C + z*M*N.
// EPI: 0 = store, 1 = C += v (residual add), 2 = C = softplus(v + bias[col]).
template<int EPI>
__global__ __launch_bounds__(256) void gemm_bt(
    const bf16* __restrict__ A, const bf16* __restrict__ B,
    float* __restrict__ C, const float* __restrict__ bias,
    int M, int N, int K, int lda, int ntm)
{
    __shared__ bf16 sA[128 * 32];
    __shared__ bf16 sB[128 * 32];
    const int bid  = blockIdx.x;
    const int m0   = (bid % ntm) * 128;
    const int n0   = (bid / ntm) * 128;
    const int koff = blockIdx.y * K;
    const int t    = threadIdx.x;
    const int wave = t >> 6;
    const int lane = t & 63;
    // staging: each wave fills a contiguous 1KB LDS chunk; lane l -> +l*16B
    const int r0 = wave * 16 + (lane >> 2);      // tile row 0..63
    const int c0 = (lane & 3) * 8;               // k element offset 0/8/16/24
    // fragment indices
    const int wm = (wave & 1) * 64;
    const int wn = (wave >> 1) * 64;
    const int fm = lane & 15;
    const int kq = (lane >> 4) * 8;

    f32x4 acc[4][4];
    #pragma unroll
    for (int i = 0; i < 4; ++i)
        #pragma unroll
        for (int j = 0; j < 4; ++j)
            acc[i][j] = {0.f, 0.f, 0.f, 0.f};

    int nr0 = n0 + r0;      if (nr0 > N - 1) nr0 = N - 1;
    int nr1 = n0 + 64 + r0; if (nr1 > N - 1) nr1 = N - 1;

    const bf16* gA0 = A + (size_t)(m0 + r0)      * lda + koff + c0;
    const bf16* gA1 = A + (size_t)(m0 + 64 + r0) * lda + koff + c0;
    const bf16* gB0 = B + (size_t)nr0 * lda + koff + c0;
    const bf16* gB1 = B + (size_t)nr1 * lda + koff + c0;
    char* lA0 = (char*)sA + wave * 1024;
    char* lA1 = (char*)sA + 4096 + wave * 1024;
    char* lB0 = (char*)sB + wave * 1024;
    char* lB1 = (char*)sB + 4096 + wave * 1024;

    C += (size_t)blockIdx.y * M * N;

    for (int k0 = 0; k0 < K; k0 += 32) {
        async_copy16(lA0, gA0 + k0);
        async_copy16(lA1, gA1 + k0);
        async_copy16(lB0, gB0 + k0);
        async_copy16(lB1, gB1 + k0);
        __syncthreads();

        bf16x8 af[4], bfr[4];
        #pragma unroll
        for (int i = 0; i < 4; ++i) {
            af[i]  = *(const bf16x8*)&sA[(wm + i * 16 + fm) * 32 + kq];
            bfr[i] = *(const bf16x8*)&sB[(wn + i * 16 + fm) * 32 + kq];
        }
        #pragma unroll
        for (int i = 0; i < 4; ++i)
            #pragma unroll
            for (int j = 0; j < 4; ++j)
                acc[i][j] = __builtin_amdgcn_mfma_f32_16x16x32_bf16(
                    af[i], bfr[j], acc[i][j], 0, 0, 0);
        __syncthreads();
    }

    // C/D layout: col = lane&15, row = (lane>>4)*4 + reg
    const int lr = (lane >> 4) * 4;
    const int lc = lane & 15;
    #pragma unroll
    for (int i = 0; i < 4; ++i) {
        #pragma unroll
        for (int j = 0; j < 4; ++j) {
            const int col = n0 + wn + j * 16 + lc;
            if (col >= N) continue;
            #pragma unroll
            for (int r = 0; r < 4; ++r) {
                const int row = m0 + wm + i * 16 + lr + r;
                const size_t o = (size_t)row * N + col;
                float v = acc[i][j][r];
                if (EPI == 1) {
                    C[o] += v;
                } else if (EPI == 2) {
                    v += bias[col];
                    v = (v > 15.f) ? v : __logf(1.f + __expf(v));
                    C[o] = v;
                } else {
                    C[o] = v;
                }
            }
        }
    }
}

// sum 4 split-K partial C slices
__global__ __launch_bounds__(256) void reduce4_kernel(
    const float* __restrict__ p, float* __restrict__ o, int n)
{
    const int i = blockIdx.x * 256 + threadIdx.x;
    if (i >= n) return;
    o[i] = p[i] + p[i + n] + p[i + 2 * n] + p[i + 3 * n];
}

// ---------------------------------------------------------------------------
__global__ __launch_bounds__(192) void embed_kernel(
    const int* __restrict__ ids, const float* __restrict__ emb,
    float* __restrict__ x)
{
    const int row = blockIdx.x;
    const int t = threadIdx.x;                       // 192 threads * float4 = 768
    const float4* src = (const float4*)(emb + (size_t)ids[row] * D_MODEL);
    float4* dst = (float4*)(x + (size_t)row * D_MODEL);
    dst[t] = src[t];
}

// ---------------------------------------------------------------------------
__global__ __launch_bounds__(256) void rmsnorm_kernel(
    const float* __restrict__ x, const float* __restrict__ w,
    bf16* __restrict__ out)
{
    const int row = blockIdx.x;
    const float* xr = x + (size_t)row * D_MODEL;
    const int t = threadIdx.x;
    float v0 = xr[t], v1 = xr[t + 256], v2 = xr[t + 512];
    float s = v0 * v0 + v1 * v1 + v2 * v2;
    #pragma unroll
    for (int m = 1; m < 64; m <<= 1) s += __shfl_xor(s, m);
    __shared__ float red[4];
    if ((t & 63) == 0) red[t >> 6] = s;
    __syncthreads();
    s = red[0] + red[1] + red[2] + red[3];
    const float sc = rsqrtf(s * (1.f / 768.f) + 1e-5f);
    bf16* o = out + (size_t)row * D_MODEL;
    o[t]       = __float2bfloat16(v0 * sc * w[t]);
    o[t + 256] = __float2bfloat16(v1 * sc * w[t + 256]);
    o[t + 512] = __float2bfloat16(v2 * sc * w[t + 512]);
}

// ---------------------------------------------------------------------------
// vectorized f32 -> bf16, 8 elements per thread (n % 8 == 0)
__global__ __launch_bounds__(256) void cvt_bf16_kernel(
    const float* __restrict__ src, bf16* __restrict__ dst, int n)
{
    const int i = (blockIdx.x * 256 + threadIdx.x) * 8;
    if (i >= n) return;
    const float4 a = *(const float4*)(src + i);
    const float4 b = *(const float4*)(src + i + 4);
    bf8 o;
    o.v[0] = __float2bfloat16(a.x); o.v[1] = __float2bfloat16(a.y);
    o.v[2] = __float2bfloat16(a.z); o.v[3] = __float2bfloat16(a.w);
    o.v[4] = __float2bfloat16(b.x); o.v[5] = __float2bfloat16(b.y);
    o.v[6] = __float2bfloat16(b.z); o.v[7] = __float2bfloat16(b.w);
    *(bf8*)(dst + i) = o;
}

// all four per-layer weight buffers in one launch (dt_proj K-padded 48->64)
__global__ __launch_bounds__(256) void cvt_layer_weights(
    const float* __restrict__ ipw, const float* __restrict__ xpw,
    const float* __restrict__ dtw, const float* __restrict__ opw,
    bf16* __restrict__ wip, bf16* __restrict__ wxp,
    bf16* __restrict__ wdt, bf16* __restrict__ wop)
{
    int i = blockIdx.x * 256 + threadIdx.x;
    if (i < 3072 * 768) { wip[i] = __float2bfloat16(ipw[i]); return; }
    i -= 3072 * 768;
    if (i < 80 * 1536)  { wxp[i] = __float2bfloat16(xpw[i]); return; }
    i -= 80 * 1536;
    if (i < 1536 * 64) {
        const int r = i >> 6, c = i & 63;
        wdt[i] = __float2bfloat16(c < DT_RANK ? dtw[r * DT_RANK + c] : 0.f);
        return;
    }
    i -= 1536 * 64;
    if (i < 768 * 1536) { wop[i] = __float2bfloat16(opw[i]); }
}

// delta_raw = x_dbl[:, 0:48], zero-padded to K=64, bf16
__global__ __launch_bounds__(256) void pad_dt_kernel(
    const float* __restrict__ x_dbl, bf16* __restrict__ out)
{
    const int i = blockIdx.x * 256 + threadIdx.x;   // 2048*64
    const int r = i >> 6, c = i & 63;
    out[i] = __float2bfloat16(c < DT_RANK ? x_dbl[r * 80 + c] : 0.f);
}

// ---------------------------------------------------------------------------
// causal depthwise conv (k=4) + bias + silu; writes f32 (for scan) + bf16 (GEMM A)
__global__ __launch_bounds__(256) void conv_silu_kernel(
    const float* __restrict__ xr, const float* __restrict__ cw,
    const float* __restrict__ cb, float* __restrict__ uf,
    bf16* __restrict__ ub)
{
    const int idx = blockIdx.x * 256 + threadIdx.x;   // < 2048*1536
    const int di  = idx % D_INNER;
    const int row = idx / D_INNER;
    const int l   = row & (SEQ - 1);
    float acc = cb[di];
    #pragma unroll
    for (int j = 0; j < 4; ++j) {
        const int ll = l - 3 + j;
        if (ll >= 0)
            acc += cw[di * 4 + j] * xr[(size_t)(row - 3 + j) * 3072 + di];
    }
    const float s = acc / (1.f + __expf(-acc));
    uf[idx] = s;
    ub[idx] = __float2bfloat16(s);
}

// ---------------------------------------------------------------------------
// Chunked selective scan. Recurrence h[t] = a[t] h[t-1] + b[t] split into
// NCHUNK chunks of LCHUNK steps.  Layout of P/H/Hin: [chunk][ch*16 + n].
//
// Pass 1: per (ch, chunk): P = prod a[t], H = local end state (zero init).
__global__ __launch_bounds__(256) void scan_pass1(
    const float* __restrict__ delta, const float* __restrict__ u,
    const float* __restrict__ x_dbl, const float* __restrict__ A_log,
    float* __restrict__ P, float* __restrict__ H)
{
    const int n  = threadIdx.x & 15;
    const int g  = threadIdx.x >> 4;
    const int ch = blockIdx.x * 16 + g;      // 0..3071
    const int k  = blockIdx.y;               // chunk
    const int b  = ch / D_INNER;
    const int di = ch % D_INNER;
    const int t0 = k * LCHUNK;

    const float An = -__expf(A_log[di * D_STATE + n]);
    const float* drow = delta + ((size_t)b * SEQ + t0) * D_INNER + di;
    const float* urow = u     + ((size_t)b * SEQ + t0) * D_INNER + di;
    const float* xdr  = x_dbl + ((size_t)b * SEQ + t0) * 80;

    float h = 0.f, ap = 1.f;
    #pragma unroll
    for (int t = 0; t < LCHUNK; ++t) {
        const float dv = drow[t * D_INNER];
        const float uv = urow[t * D_INNER];
        const float Bv = xdr[t * 80 + 48 + n];
        const float a  = __expf(dv * An);
        h = a * h + (dv * Bv) * uv;
        ap *= a;
    }
    const size_t o = (size_t)k * CHST + ch * 16 + n;
    P[o] = ap;
    H[o] = h;
}

// Pass 2: serial combine across chunks; emits each chunk's initial state.
__global__ __launch_bounds__(256) void scan_pass2(
    const float* __restrict__ P, const float* __restrict__ H,
    float* __restrict__ Hin)
{
    const int id = blockIdx.x * 256 + threadIdx.x;   // < CHST
    float h = 0.f;
    #pragma unroll 16
    for (int k = 0; k < NCHUNK; ++k) {
        const size_t o = (size_t)k * CHST + id;
        Hin[o] = h;
        h = P[o] * h + H[o];
    }
}

// Pass 3: re-scan each chunk from Hin; C-dot via shfl reduce; epilogue fused.
__global__ __launch_bounds__(256) void scan_pass3(
    const float* __restrict__ delta, const float* __restrict__ u,
    const float* __restrict__ x_dbl, const float* __restrict__ xr,
    const float* __restrict__ A_log, const float* __restrict__ Dp,
    const float* __restrict__ Hin, bf16* __restrict__ yb)
{
    const int n  = threadIdx.x & 15;
    const int g  = threadIdx.x >> 4;
    const int ch = blockIdx.x * 16 + g;
    const int k  = blockIdx.y;
    const int b  = ch / D_INNER;
    const int di = ch % D_INNER;
    const int t0 = k * LCHUNK;

    const float An = -__expf(A_log[di * D_STATE + n]);
    const float Dv = Dp[di];
    const float* drow = delta + ((size_t)b * SEQ + t0) * D_INNER + di;
    const float* urow = u     + ((size_t)b * SEQ + t0) * D_INNER + di;
    const float* rrow = xr + ((size_t)b * SEQ + t0) * 3072 + D_INNER + di;
    const float* xdr  = x_dbl + ((size_t)b * SEQ + t0) * 80;
    bf16* yrow = yb + ((size_t)b * SEQ + t0) * D_INNER + di;

    float h = Hin[(size_t)k * CHST + ch * 16 + n];
    #pragma unroll
    for (int t = 0; t < LCHUNK; ++t) {
        const float dv = drow[t * D_INNER];
        const float uv = urow[t * D_INNER];
        const float Bv = xdr[t * 80 + 48 + n];
        const float Cv = xdr[t * 80 + 64 + n];
        const float a  = __expf(dv * An);
        h = a * h + (dv * Bv) * uv;
        float p = h * Cv;
        p += __shfl_xor(p, 1);
        p += __shfl_xor(p, 2);
        p += __shfl_xor(p, 4);
        p += __shfl_xor(p, 8);
        if (n == 0) {
            float y = p + uv * Dv;
            const float r = rrow[t * 3072];
            y *= r / (1.f + __expf(-r));       // * silu(res)
            yrow[t * D_INNER] = __float2bfloat16(y);
        }
    }
}

// ---------------------------------------------------------------------------
extern "C" void kernel_launch(void* const* d_in, const int* in_sizes, int n_in,
                              void* d_out, int out_size, void* d_ws, size_t ws_size,
                              hipStream_t stream)
{
    const int*   ids    = (const int*)  d_in[0];
    const float* emb    = (const float*)d_in[1];
    const float* norm_w = (const float*)d_in[2];
    const float* ipw    = (const float*)d_in[3];
    const float* cw     = (const float*)d_in[4];
    const float* cb     = (const float*)d_in[5];
    const float* xpw    = (const float*)d_in[6];
    const float* dtw    = (const float*)d_in[7];
    const float* dtb    = (const float*)d_in[8];
    const float* alog   = (const float*)d_in[9];
    const float* Dp     = (const float*)d_in[10];
    const float* opw    = (const float*)d_in[11];
    const float* nfw    = (const float*)d_in[12];
    float* out = (float*)d_out;

    // -------- workspace layout (~79.6 MB) --------
    char* ws = (char*)d_ws;
    bf16*  emb_bf = (bf16*)ws;  ws += (size_t)VOCAB * D_MODEL * 2;
    float* x      = (float*)ws; ws += (size_t)NROWS * D_MODEL * 4;
    bf16*  xn     = (bf16*)ws;  ws += (size_t)NROWS * D_MODEL * 2;
    bf16*  ub     = (bf16*)ws;  ws += (size_t)NROWS * D_INNER * 2;
    float* xdbl   = (float*)ws; ws += (size_t)NROWS * 80 * 4;
    bf16*  dtraw  = (bf16*)ws;  ws += (size_t)NROWS * 64 * 2;
    bf16*  yb     = (bf16*)ws;  ws += (size_t)NROWS * D_INNER * 2;
    bf16*  wip    = (bf16*)ws;  ws += (size_t)3072 * 768 * 2;
    bf16*  wxp    = (bf16*)ws;  ws += (size_t)80 * 1536 * 2;
    bf16*  wdt    = (bf16*)ws;  ws += (size_t)1536 * 64 * 2;
    bf16*  wop    = (bf16*)ws;  ws += (size_t)768 * 1536 * 2;

    // -------- big transients live in d_out (262 MB), overwritten by logits --------
    char* ob = (char*)d_out;
    float* xr    = (float*)ob;  ob += (size_t)NROWS * 3072 * 4;      // 25.2 MB
    float* uf    = (float*)ob;  ob += (size_t)NROWS * D_INNER * 4;   // 12.6 MB
    float* delta = (float*)ob;  ob += (size_t)NROWS * D_INNER * 4;   // 12.6 MB
    float* Pbuf  = (float*)ob;  ob += (size_t)NCHUNK * CHST * 4;     // 12.6 MB
    float* Hbuf  = (float*)ob;  ob += (size_t)NCHUNK * CHST * 4;     // 12.6 MB
    float* Hin   = (float*)ob;  ob += (size_t)NCHUNK * CHST * 4;     // 12.6 MB
    float* xpart = (float*)ob;  ob += (size_t)4 * NROWS * 80 * 4;    //  2.6 MB

    cvt_bf16_kernel<<<VOCAB * D_MODEL / 8 / 256, 256, 0, stream>>>(
        emb, emb_bf, VOCAB * D_MODEL);
    embed_kernel<<<NROWS, 192, 0, stream>>>(ids, emb, x);

    for (int l = 0; l < 2; ++l) {
        cvt_layer_weights<<<(3760128 + 255) / 256, 256, 0, stream>>>(
            ipw + (size_t)l * 3072 * 768, xpw + (size_t)l * 80 * 1536,
            dtw + (size_t)l * 1536 * DT_RANK, opw + (size_t)l * 768 * 1536,
            wip, wxp, wdt, wop);
        rmsnorm_kernel<<<NROWS, 256, 0, stream>>>(x, norm_w + l * D_MODEL, xn);
        // in_proj: (2048x768)(3072x768)^T -> xr
        gemm_bt<0><<<16 * 24, 256, 0, stream>>>(xn, wip, xr, nullptr,
                                                NROWS, 3072, D_MODEL, D_MODEL, 16);
        conv_silu_kernel<<<NROWS * D_INNER / 256, 256, 0, stream>>>(
            xr, cw + (size_t)l * D_INNER * 4, cb + (size_t)l * D_INNER, uf, ub);
        // x_proj: (2048x1536)(80x1536)^T -> x_dbl, split-K x4 (16 blocks -> 64)
        gemm_bt<0><<<dim3(16, 4), 256, 0, stream>>>(ub, wxp, xpart, nullptr,
                                                    NROWS, 80, 384, D_INNER, 16);
        reduce4_kernel<<<(NROWS * 80 + 255) / 256, 256, 0, stream>>>(
            xpart, xdbl, NROWS * 80);
        pad_dt_kernel<<<NROWS * 64 / 256, 256, 0, stream>>>(xdbl, dtraw);
        // dt_proj + softplus: (2048x64)(1536x64)^T -> delta
        gemm_bt<2><<<16 * 12, 256, 0, stream>>>(dtraw, wdt, delta,
                                                dtb + (size_t)l * D_INNER,
                                                NROWS, D_INNER, 64, 64, 16);
        // chunked selective scan
        scan_pass1<<<dim3(192, NCHUNK), 256, 0, stream>>>(
            delta, uf, xdbl, alog + (size_t)l * D_INNER * D_STATE, Pbuf, Hbuf);
        scan_pass2<<<CHST / 256, 256, 0, stream>>>(Pbuf, Hbuf, Hin);
        scan_pass3<<<dim3(192, NCHUNK), 256, 0, stream>>>(
            delta, uf, xdbl, xr, alog + (size_t)l * D_INNER * D_STATE,
            Dp + (size_t)l * D_INNER, Hin, yb);
        // out_proj with residual add into x
        gemm_bt<1><<<16 * 6, 256, 0, stream>>>(yb, wop, x, nullptr,
                                               NROWS, D_MODEL, D_INNER, D_INNER, 16);
    }

    rmsnorm_kernel<<<NROWS, 256, 0, stream>>>(x, nfw, xn);
    // logits: (2048x768)(32000x768)^T -> out  [256^2 8-phase kernel, 1000 blocks]
    gemm256<<<8 * 125, 512, 0, stream>>>(xn, emb_bf, out,
                                         NROWS, VOCAB, D_MODEL, 8);
}

// Round 3
// 885.031 us; speedup vs baseline: 1.1907x; 1.0975x over previous
//
#include <hip/hip_runtime.h>
#include <hip/hip_bf16.h>
#include <cstdint>
#include <cstddef>

#define D_MODEL 768
#define D_INNER 1536
#define DT_RANK 48
#define D_STATE 16
#define SEQ     1024
#define BATCH   2
#define NROWS   2048      // BATCH*SEQ
#define VOCAB   32000
#define LCHUNK  32
#define NCHUNK  32        // SEQ / LCHUNK
#define CHST    49152     // 3072 channels * 16 states

typedef __hip_bfloat16 bf16;
typedef short bf16x8 __attribute__((ext_vector_type(8)));   // 8 bf16 in 4 VGPRs
typedef float f32x4  __attribute__((ext_vector_type(4)));
struct bf8 { bf16 v[8]; };

// ---------------------------------------------------------------------------
// async global->LDS, 16B per lane. LDS dest = wave-uniform base + lane*16.
__device__ __forceinline__ void async_copy16(void* lds, const void* gp) {
    __builtin_amdgcn_global_load_lds(
        (const __attribute__((address_space(1))) unsigned int*)gp,
        (__attribute__((address_space(3)))       unsigned int*)lds,
        16, 0, 0);
}

// ===========================================================================
// gemm256: 256x256 tile, BK=64, 8 waves (2Mx4N), 128 KiB LDS double buffer,
// 8-phase schedule with counted vmcnt (T3+T4), XOR chunk swizzle (T2, applied
// as linear LDS dest + inverse-swizzled GLOBAL source + swizzled ds_read),
// setprio around MFMA (T5), bijective XCD blockIdx swizzle (T1).
// Requirements: M%256==0, N%256==0, K%128==0, grid = (M/256)*(N/256) % 8 == 0.
// C = A(M,K) * B(N,K)^T, bf16 in / f32 out.  [verified round 1: ~100us]
// ===========================================================================

#define LDSP(BUF, AB) (smem + (((BUF)*2 + (AB)) << 15))

#define PHB() do { \
  __builtin_amdgcn_sched_barrier(0); \
  __builtin_amdgcn_s_barrier(); \
  __builtin_amdgcn_sched_barrier(0); \
} while (0)

#define WAIT_VMCNT(n) do { \
  asm volatile("s_waitcnt vmcnt(" #n ")" ::: "memory"); \
  __builtin_amdgcn_sched_barrier(0); \
} while (0)

#define STAGE_A(BUF, H, KT) do { \
  const int ru0_ = (H)*64 + wave*8; \
  const int ru1_ = ru0_ + 128; \
  const bf16* ga0_ = Ag + (size_t)(m0 + ru0_ + (lane >> 3)) * (size_t)K + (size_t)((KT)*64 + swz8); \
  const bf16* ga1_ = Ag + (size_t)(m0 + ru1_ + (lane >> 3)) * (size_t)K + (size_t)((KT)*64 + swz8); \
  async_copy16(LDSP(BUF, 0) + ru0_*128, ga0_); \
  async_copy16(LDSP(BUF, 0) + ru1_*128, ga1_); \
} while (0)

#define STAGE_B(BUF, H, KT) do { \
  const int lb0_ = wave*8, lb1_ = 64 + wave*8; \
  const int rb0_ = ((lb0_ >> 5) << 6) + (H)*32 + (lb0_ & 31); \
  const int rb1_ = ((lb1_ >> 5) << 6) + (H)*32 + (lb1_ & 31); \
  const bf16* gb0_ = Bg + (size_t)(n0 + rb0_ + (lane >> 3)) * (size_t)K + (size_t)((KT)*64 + swz8); \
  const bf16* gb1_ = Bg + (size_t)(n0 + rb1_ + (lane >> 3)) * (size_t)K + (size_t)((KT)*64 + swz8); \
  async_copy16(LDSP(BUF, 1) + rb0_*128, gb0_); \
  async_copy16(LDSP(BUF, 1) + rb1_*128, gb1_); \
} while (0)

#define RDA4(BUF, MH) do { \
  _Pragma("unroll") \
  for (int i2_ = 0; i2_ < 4; ++i2_) { \
    const char* rp_ = LDSP(BUF, 0) + (wr*128 + (MH)*64 + i2_*16 + fm) * 128; \
    a[i2_][0] = *(const bf16x8*)(rp_ + (((kqi    ) ^ fm7) << 4)); \
    a[i2_][1] = *(const bf16x8*)(rp_ + (((4 + kqi) ^ fm7) << 4)); \
  } \
} while (0)

#define RDB4(BUF, NH, DST) do { \
  _Pragma("unroll") \
  for (int j2_ = 0; j2_ < 2; ++j2_) { \
    const char* rp_ = LDSP(BUF, 1) + (wc*64 + (NH)*32 + j2_*16 + fm) * 128; \
    DST[j2_][0] = *(const bf16x8*)(rp_ + (((kqi    ) ^ fm7) << 4)); \
    DST[j2_][1] = *(const bf16x8*)(rp_ + (((4 + kqi) ^ fm7) << 4)); \
  } \
} while (0)

#define QMFMA(MH, NH, BB) do { \
  __builtin_amdgcn_s_setprio(1); \
  _Pragma("unroll") \
  for (int i2_ = 0; i2_ < 4; ++i2_) { \
    _Pragma("unroll") \
    for (int j2_ = 0; j2_ < 2; ++j2_) { \
      acc[(MH)*4 + i2_][(NH)*2 + j2_] = __builtin_amdgcn_mfma_f32_16x16x32_bf16( \
          a[i2_][0], BB[j2_][0], acc[(MH)*4 + i2_][(NH)*2 + j2_], 0, 0, 0); \
      acc[(MH)*4 + i2_][(NH)*2 + j2_] = __builtin_amdgcn_mfma_f32_16x16x32_bf16( \
          a[i2_][1], BB[j2_][1], acc[(MH)*4 + i2_][(NH)*2 + j2_], 0, 0, 0); \
    } \
  } \
  __builtin_amdgcn_s_setprio(0); \
} while (0)

#define ITER(TT, LAST) do { \
  RDA4(0, 0); RDB4(0, 0, b0); \
  STAGE_B(1, 1, (TT) + 1); \
  PHB(); QMFMA(0, 0, b0); PHB(); \
  RDB4(0, 1, b1); \
  if (!(LAST)) STAGE_A(0, 0, (TT) + 2); \
  PHB(); QMFMA(0, 1, b1); PHB(); \
  RDA4(0, 1); \
  if (!(LAST)) STAGE_B(0, 0, (TT) + 2); \
  PHB(); QMFMA(1, 0, b0); PHB(); \
  if (!(LAST)) { STAGE_A(0, 1, (TT) + 2); WAIT_VMCNT(6); } else { WAIT_VMCNT(0); } \
  PHB(); QMFMA(1, 1, b1); PHB(); \
  RDA4(1, 0); RDB4(1, 0, b0); \
  if (!(LAST)) STAGE_B(0, 1, (TT) + 2); \
  PHB(); QMFMA(0, 0, b0); PHB(); \
  RDB4(1, 1, b1); \
  if (!(LAST)) STAGE_A(1, 0, (TT) + 3); \
  PHB(); QMFMA(0, 1, b1); PHB(); \
  RDA4(1, 1); \
  if (!(LAST)) STAGE_B(1, 0, (TT) + 3); \
  PHB(); QMFMA(1, 0, b0); PHB(); \
  if (!(LAST)) { STAGE_A(1, 1, (TT) + 3); WAIT_VMCNT(6); } else { WAIT_VMCNT(0); } \
  PHB(); QMFMA(1, 1, b1); PHB(); \
} while (0)

__global__ __launch_bounds__(512, 2) void gemm256(
    const bf16* __restrict__ Ag, const bf16* __restrict__ Bg,
    float* __restrict__ C, int M, int N, int K, int ntm)
{
    (void)M;
    __shared__ __align__(16) char smem[131072];   // [buf][A/B] 4 x 32KB

    const int cpx  = gridDim.x >> 3;
    const int bid  = blockIdx.x;
    const int wgid = (bid & 7) * cpx + (bid >> 3);
    const int m0 = (wgid % ntm) << 8;
    const int n0 = (wgid / ntm) << 8;

    const int t    = threadIdx.x;
    const int wave = t >> 6, lane = t & 63;
    const int wr = wave >> 2, wc = wave & 3;     // 2 x 4 wave grid
    const int fm  = lane & 15, fm7 = lane & 7;
    const int kqi = lane >> 4;
    const int swz8 = (((lane & 7) ^ ((lane >> 3) & 7)) << 3);
    const int nkt = K >> 6;

    f32x4 acc[8][4];
    #pragma unroll
    for (int i = 0; i < 8; ++i)
        #pragma unroll
        for (int j = 0; j < 4; ++j)
            acc[i][j] = {0.f, 0.f, 0.f, 0.f};

    bf16x8 a[4][2], b0[2][2], b1[2][2];

    STAGE_A(0, 0, 0); STAGE_A(0, 1, 0); STAGE_B(0, 0, 0); STAGE_B(0, 1, 0);
    WAIT_VMCNT(4);
    STAGE_A(1, 0, 1); STAGE_A(1, 1, 1); STAGE_B(1, 0, 1);
    WAIT_VMCNT(6);
    PHB();

    int tt = 0;
    #pragma unroll 1
    for (; tt + 2 < nkt; tt += 2) { ITER(tt, false); }
    ITER(tt, true);

    const int lr = (lane >> 4) * 4;
    const int lc = lane & 15;
    #pragma unroll
    for (int i = 0; i < 8; ++i) {
        #pragma unroll
        for (int j = 0; j < 4; ++j) {
            const size_t base = (size_t)(m0 + wr*128 + i*16 + lr) * N
                              + (size_t)(n0 + wc*64 + j*16 + lc);
            #pragma unroll
            for (int r = 0; r < 4; ++r)
                C[base + (size_t)r * N] = acc[i][j][r];
        }
    }
}

// ---------------------------------------------------------------------------
// GEMM: C(M,N) = A(M,K) * B(N,K)^T.  A,B bf16 row-major (lda = leading dim),
// K = depth this launch processes.  blockIdx.y = split-K slice: reads cols
// [z*K, (z+1)*K), writes partial to C + z*M*N.
// EPI: 0 = store, 1 = C += v (residual add), 2 = C = softplus(v + bias[col]).
template<int EPI>
__global__ __launch_bounds__(256) void gemm_bt(
    const bf16* __restrict__ A, const bf16* __restrict__ B,
    float* __restrict__ C, const float* __restrict__ bias,
    int M, int N, int K, int lda, int ntm)
{
    __shared__ bf16 sA[128 * 32];
    __shared__ bf16 sB[128 * 32];
    const int bid  = blockIdx.x;
    const int m0   = (bid % ntm) * 128;
    const int n0   = (bid / ntm) * 128;
    const int koff = blockIdx.y * K;
    const int t    = threadIdx.x;
    const int wave = t >> 6;
    const int lane = t & 63;
    const int r0 = wave * 16 + (lane >> 2);      // tile row 0..63
    const int c0 = (lane & 3) * 8;               // k element offset 0/8/16/24
    const int wm = (wave & 1) * 64;
    const int wn = (wave >> 1) * 64;
    const int fm = lane & 15;
    const int kq = (lane >> 4) * 8;

    f32x4 acc[4][4];
    #pragma unroll
    for (int i = 0; i < 4; ++i)
        #pragma unroll
        for (int j = 0; j < 4; ++j)
            acc[i][j] = {0.f, 0.f, 0.f, 0.f};

    int nr0 = n0 + r0;      if (nr0 > N - 1) nr0 = N - 1;
    int nr1 = n0 + 64 + r0; if (nr1 > N - 1) nr1 = N - 1;

    const bf16* gA0 = A + (size_t)(m0 + r0)      * lda + koff + c0;
    const bf16* gA1 = A + (size_t)(m0 + 64 + r0) * lda + koff + c0;
    const bf16* gB0 = B + (size_t)nr0 * lda + koff + c0;
    const bf16* gB1 = B + (size_t)nr1 * lda + koff + c0;
    char* lA0 = (char*)sA + wave * 1024;
    char* lA1 = (char*)sA + 4096 + wave * 1024;
    char* lB0 = (char*)sB + wave * 1024;
    char* lB1 = (char*)sB + 4096 + wave * 1024;

    C += (size_t)blockIdx.y * M * N;

    for (int k0 = 0; k0 < K; k0 += 32) {
        async_copy16(lA0, gA0 + k0);
        async_copy16(lA1, gA1 + k0);
        async_copy16(lB0, gB0 + k0);
        async_copy16(lB1, gB1 + k0);
        __syncthreads();

        bf16x8 af[4], bfr[4];
        #pragma unroll
        for (int i = 0; i < 4; ++i) {
            af[i]  = *(const bf16x8*)&sA[(wm + i * 16 + fm) * 32 + kq];
            bfr[i] = *(const bf16x8*)&sB[(wn + i * 16 + fm) * 32 + kq];
        }
        #pragma unroll
        for (int i = 0; i < 4; ++i)
            #pragma unroll
            for (int j = 0; j < 4; ++j)
                acc[i][j] = __builtin_amdgcn_mfma_f32_16x16x32_bf16(
                    af[i], bfr[j], acc[i][j], 0, 0, 0);
        __syncthreads();
    }

    const int lr = (lane >> 4) * 4;
    const int lc = lane & 15;
    #pragma unroll
    for (int i = 0; i < 4; ++i) {
        #pragma unroll
        for (int j = 0; j < 4; ++j) {
            const int col = n0 + wn + j * 16 + lc;
            if (col >= N) continue;
            #pragma unroll
            for (int r = 0; r < 4; ++r) {
                const int row = m0 + wm + i * 16 + lr + r;
                const size_t o = (size_t)row * N + col;
                float v = acc[i][j][r];
                if (EPI == 1) {
                    C[o] += v;
                } else if (EPI == 2) {
                    v += bias[col];
                    v = (v > 15.f) ? v : __logf(1.f + __expf(v));
                    C[o] = v;
                } else {
                    C[o] = v;
                }
            }
        }
    }
}

// ---------------------------------------------------------------------------
// x_proj split-K reduce: xdbl = sum of 4 partial slices; also emits dtraw
// (delta cols 0..47 zero-padded to 64, bf16) -- fuses pad_dt.
__global__ __launch_bounds__(256) void reduce_xp_kernel(
    const float* __restrict__ p, float* __restrict__ xdbl,
    bf16* __restrict__ dtraw)
{
    const int i = blockIdx.x * 256 + threadIdx.x;   // < NROWS*80
    const float v = p[i] + p[i + 163840] + p[i + 327680] + p[i + 491520];
    xdbl[i] = v;
    const int r = i / 80, c = i - r * 80;
    if (c < 64)
        dtraw[(r << 6) + c] = __float2bfloat16(c < DT_RANK ? v : 0.f);
}

// ---------------------------------------------------------------------------
// out_proj split-K reduce + residual add into x + rmsnorm -> xn (bf16).
// Fuses: reduce4, residual add, and the NEXT layer's (or final) rmsnorm.
__global__ __launch_bounds__(256) void reduce_res_norm_kernel(
    const float* __restrict__ part, float* __restrict__ x,
    const float* __restrict__ w, bf16* __restrict__ out)
{
    const int row = blockIdx.x;
    const size_t base = (size_t)row * D_MODEL;
    const int t = threadIdx.x;
    float v0, v1, v2;
    {
        const int e0 = t, e1 = t + 256, e2 = t + 512;
        v0 = x[base + e0] + part[base + e0] + part[base + e0 + 1572864]
           + part[base + e0 + 3145728] + part[base + e0 + 4718592];
        v1 = x[base + e1] + part[base + e1] + part[base + e1 + 1572864]
           + part[base + e1 + 3145728] + part[base + e1 + 4718592];
        v2 = x[base + e2] + part[base + e2] + part[base + e2 + 1572864]
           + part[base + e2 + 3145728] + part[base + e2 + 4718592];
    }
    // store residual stream
    x[base + t]       = v0;
    x[base + t + 256] = v1;
    x[base + t + 512] = v2;
    // rmsnorm
    float s = v0 * v0 + v1 * v1 + v2 * v2;
    #pragma unroll
    for (int m = 1; m < 64; m <<= 1) s += __shfl_xor(s, m);
    __shared__ float red[4];
    if ((t & 63) == 0) red[t >> 6] = s;
    __syncthreads();
    s = red[0] + red[1] + red[2] + red[3];
    const float sc = rsqrtf(s * (1.f / 768.f) + 1e-5f);
    bf16* o = out + base;
    o[t]       = __float2bfloat16(v0 * sc * w[t]);
    o[t + 256] = __float2bfloat16(v1 * sc * w[t + 256]);
    o[t + 512] = __float2bfloat16(v2 * sc * w[t + 512]);
}

// ---------------------------------------------------------------------------
__global__ __launch_bounds__(192) void embed_kernel(
    const int* __restrict__ ids, const float* __restrict__ emb,
    float* __restrict__ x)
{
    const int row = blockIdx.x;
    const int t = threadIdx.x;                       // 192 threads * float4 = 768
    const float4* src = (const float4*)(emb + (size_t)ids[row] * D_MODEL);
    float4* dst = (float4*)(x + (size_t)row * D_MODEL);
    dst[t] = src[t];
}

// ---------------------------------------------------------------------------
__global__ __launch_bounds__(256) void rmsnorm_kernel(
    const float* __restrict__ x, const float* __restrict__ w,
    bf16* __restrict__ out)
{
    const int row = blockIdx.x;
    const float* xr = x + (size_t)row * D_MODEL;
    const int t = threadIdx.x;
    float v0 = xr[t], v1 = xr[t + 256], v2 = xr[t + 512];
    float s = v0 * v0 + v1 * v1 + v2 * v2;
    #pragma unroll
    for (int m = 1; m < 64; m <<= 1) s += __shfl_xor(s, m);
    __shared__ float red[4];
    if ((t & 63) == 0) red[t >> 6] = s;
    __syncthreads();
    s = red[0] + red[1] + red[2] + red[3];
    const float sc = rsqrtf(s * (1.f / 768.f) + 1e-5f);
    bf16* o = out + (size_t)row * D_MODEL;
    o[t]       = __float2bfloat16(v0 * sc * w[t]);
    o[t + 256] = __float2bfloat16(v1 * sc * w[t + 256]);
    o[t + 512] = __float2bfloat16(v2 * sc * w[t + 512]);
}

// ---------------------------------------------------------------------------
// vectorized f32 -> bf16, 8 elements per thread (n % 8 == 0)
__global__ __launch_bounds__(256) void cvt_bf16_kernel(
    const float* __restrict__ src, bf16* __restrict__ dst, int n)
{
    const int i = (blockIdx.x * 256 + threadIdx.x) * 8;
    if (i >= n) return;
    const float4 a = *(const float4*)(src + i);
    const float4 b = *(const float4*)(src + i + 4);
    bf8 o;
    o.v[0] = __float2bfloat16(a.x); o.v[1] = __float2bfloat16(a.y);
    o.v[2] = __float2bfloat16(a.z); o.v[3] = __float2bfloat16(a.w);
    o.v[4] = __float2bfloat16(b.x); o.v[5] = __float2bfloat16(b.y);
    o.v[6] = __float2bfloat16(b.z); o.v[7] = __float2bfloat16(b.w);
    *(bf8*)(dst + i) = o;
}

// BOTH layers' weight buffers in one launch (dt_proj K-padded 48->64).
// i space: [layer][ip 3072*768 | xp 80*1536 | dt 1536*64 | op 768*1536]
__global__ __launch_bounds__(256) void cvt_layer_weights(
    const float* __restrict__ ipw, const float* __restrict__ xpw,
    const float* __restrict__ dtw, const float* __restrict__ opw,
    bf16* __restrict__ wip, bf16* __restrict__ wxp,
    bf16* __restrict__ wdt, bf16* __restrict__ wop)
{
    int i = blockIdx.x * 256 + threadIdx.x;
    const int l = (i >= 3760128) ? 1 : 0;
    i -= l * 3760128;
    if (i < 3072 * 768) {
        wip[l * 3072 * 768 + i] = __float2bfloat16(ipw[l * 3072 * 768 + i]);
        return;
    }
    i -= 3072 * 768;
    if (i < 80 * 1536) {
        wxp[l * 80 * 1536 + i] = __float2bfloat16(xpw[l * 80 * 1536 + i]);
        return;
    }
    i -= 80 * 1536;
    if (i < 1536 * 64) {
        const int r = i >> 6, c = i & 63;
        wdt[l * 1536 * 64 + i] = __float2bfloat16(
            c < DT_RANK ? dtw[l * 1536 * DT_RANK + r * DT_RANK + c] : 0.f);
        return;
    }
    i -= 1536 * 64;
    wop[l * 768 * 1536 + i] = __float2bfloat16(opw[l * 768 * 1536 + i]);
}

// ---------------------------------------------------------------------------
// causal depthwise conv (k=4) + bias + silu; writes f32 (for scan) + bf16 (GEMM A)
__global__ __launch_bounds__(256) void conv_silu_kernel(
    const float* __restrict__ xr, const float* __restrict__ cw,
    const float* __restrict__ cb, float* __restrict__ uf,
    bf16* __restrict__ ub)
{
    const int idx = blockIdx.x * 256 + threadIdx.x;   // < 2048*1536
    const int di  = idx % D_INNER;
    const int row = idx / D_INNER;
    const int l   = row & (SEQ - 1);
    float acc = cb[di];
    #pragma unroll
    for (int j = 0; j < 4; ++j) {
        const int ll = l - 3 + j;
        if (ll >= 0)
            acc += cw[di * 4 + j] * xr[(size_t)(row - 3 + j) * 3072 + di];
    }
    const float s = acc / (1.f + __expf(-acc));
    uf[idx] = s;
    ub[idx] = __float2bfloat16(s);
}

// ---------------------------------------------------------------------------
// Chunked selective scan, LCHUNK=32 / NCHUNK=32.
// Pass 1: per (ch, chunk): P = prod a[t], H = local end state (zero init).
__global__ __launch_bounds__(256) void scan_pass1(
    const float* __restrict__ delta, const float* __restrict__ u,
    const float* __restrict__ x_dbl, const float* __restrict__ A_log,
    float* __restrict__ P, float* __restrict__ H)
{
    const int n  = threadIdx.x & 15;
    const int g  = threadIdx.x >> 4;
    const int ch = blockIdx.x * 16 + g;      // 0..3071
    const int k  = blockIdx.y;               // chunk
    const int b  = ch / D_INNER;
    const int di = ch % D_INNER;
    const int t0 = k * LCHUNK;

    const float An = -__expf(A_log[di * D_STATE + n]);
    const float* drow = delta + ((size_t)b * SEQ + t0) * D_INNER + di;
    const float* urow = u     + ((size_t)b * SEQ + t0) * D_INNER + di;
    const float* xdr  = x_dbl + ((size_t)b * SEQ + t0) * 80;

    float h = 0.f, ap = 1.f;
    #pragma unroll
    for (int t = 0; t < LCHUNK; ++t) {
        const float dv = drow[t * D_INNER];
        const float uv = urow[t * D_INNER];
        const float Bv = xdr[t * 80 + 48 + n];
        const float a  = __expf(dv * An);
        h = a * h + (dv * Bv) * uv;
        ap *= a;
    }
    const size_t o = (size_t)k * CHST + ch * 16 + n;
    P[o] = ap;
    H[o] = h;
}

// Pass 2: serial combine across chunks; emits each chunk's initial state.
__global__ __launch_bounds__(256) void scan_pass2(
    const float* __restrict__ P, const float* __restrict__ H,
    float* __restrict__ Hin)
{
    const int id = blockIdx.x * 256 + threadIdx.x;   // < CHST
    float h = 0.f;
    #pragma unroll
    for (int k = 0; k < NCHUNK; ++k) {
        const size_t o = (size_t)k * CHST + id;
        Hin[o] = h;
        h = P[o] * h + H[o];
    }
}

// Pass 3: re-scan each chunk from Hin; C-dot via shfl reduce; epilogue fused.
__global__ __launch_bounds__(256) void scan_pass3(
    const float* __restrict__ delta, const float* __restrict__ u,
    const float* __restrict__ x_dbl, const float* __restrict__ xr,
    const float* __restrict__ A_log, const float* __restrict__ Dp,
    const float* __restrict__ Hin, bf16* __restrict__ yb)
{
    const int n  = threadIdx.x & 15;
    const int g  = threadIdx.x >> 4;
    const int ch = blockIdx.x * 16 + g;
    const int k  = blockIdx.y;
    const int b  = ch / D_INNER;
    const int di = ch % D_INNER;
    const int t0 = k * LCHUNK;

    const float An = -__expf(A_log[di * D_STATE + n]);
    const float Dv = Dp[di];
    const float* drow = delta + ((size_t)b * SEQ + t0) * D_INNER + di;
    const float* urow = u     + ((size_t)b * SEQ + t0) * D_INNER + di;
    const float* rrow = xr + ((size_t)b * SEQ + t0) * 3072 + D_INNER + di;
    const float* xdr  = x_dbl + ((size_t)b * SEQ + t0) * 80;
    bf16* yrow = yb + ((size_t)b * SEQ + t0) * D_INNER + di;

    float h = Hin[(size_t)k * CHST + ch * 16 + n];
    #pragma unroll
    for (int t = 0; t < LCHUNK; ++t) {
        const float dv = drow[t * D_INNER];
        const float uv = urow[t * D_INNER];
        const float Bv = xdr[t * 80 + 48 + n];
        const float Cv = xdr[t * 80 + 64 + n];
        const float a  = __expf(dv * An);
        h = a * h + (dv * Bv) * uv;
        float p = h * Cv;
        p += __shfl_xor(p, 1);
        p += __shfl_xor(p, 2);
        p += __shfl_xor(p, 4);
        p += __shfl_xor(p, 8);
        if (n == 0) {
            float y = p + uv * Dv;
            const float r = rrow[t * 3072];
            y *= r / (1.f + __expf(-r));       // * silu(res)
            yrow[t * D_INNER] = __float2bfloat16(y);
        }
    }
}

// ---------------------------------------------------------------------------
extern "C" void kernel_launch(void* const* d_in, const int* in_sizes, int n_in,
                              void* d_out, int out_size, void* d_ws, size_t ws_size,
                              hipStream_t stream)
{
    const int*   ids    = (const int*)  d_in[0];
    const float* emb    = (const float*)d_in[1];
    const float* norm_w = (const float*)d_in[2];
    const float* ipw    = (const float*)d_in[3];
    const float* cw     = (const float*)d_in[4];
    const float* cb     = (const float*)d_in[5];
    const float* xpw    = (const float*)d_in[6];
    const float* dtw    = (const float*)d_in[7];
    const float* dtb    = (const float*)d_in[8];
    const float* alog   = (const float*)d_in[9];
    const float* Dp     = (const float*)d_in[10];
    const float* opw    = (const float*)d_in[11];
    const float* nfw    = (const float*)d_in[12];
    float* out = (float*)d_out;

    // -------- workspace layout (~87 MB) --------
    char* ws = (char*)d_ws;
    bf16*  emb_bf = (bf16*)ws;  ws += (size_t)VOCAB * D_MODEL * 2;
    float* x      = (float*)ws; ws += (size_t)NROWS * D_MODEL * 4;
    bf16*  xn     = (bf16*)ws;  ws += (size_t)NROWS * D_MODEL * 2;
    bf16*  ub     = (bf16*)ws;  ws += (size_t)NROWS * D_INNER * 2;
    float* xdbl   = (float*)ws; ws += (size_t)NROWS * 80 * 4;
    bf16*  dtraw  = (bf16*)ws;  ws += (size_t)NROWS * 64 * 2;
    bf16*  yb     = (bf16*)ws;  ws += (size_t)NROWS * D_INNER * 2;
    bf16*  wip    = (bf16*)ws;  ws += (size_t)2 * 3072 * 768 * 2;
    bf16*  wxp    = (bf16*)ws;  ws += (size_t)2 * 80 * 1536 * 2;
    bf16*  wdt    = (bf16*)ws;  ws += (size_t)2 * 1536 * 64 * 2;
    bf16*  wop    = (bf16*)ws;  ws += (size_t)2 * 768 * 1536 * 2;

    // -------- big transients live in d_out (262 MB), overwritten by logits --------
    char* ob = (char*)d_out;
    float* xr    = (float*)ob;  ob += (size_t)NROWS * 3072 * 4;      // 25.2 MB
    float* uf    = (float*)ob;  ob += (size_t)NROWS * D_INNER * 4;   // 12.6 MB
    float* delta = (float*)ob;  ob += (size_t)NROWS * D_INNER * 4;   // 12.6 MB
    float* Pbuf  = (float*)ob;  ob += (size_t)NCHUNK * CHST * 4;     //  6.3 MB
    float* Hbuf  = (float*)ob;  ob += (size_t)NCHUNK * CHST * 4;     //  6.3 MB
    float* Hin   = (float*)ob;  ob += (size_t)NCHUNK * CHST * 4;     //  6.3 MB
    float* xpart = (float*)ob;  ob += (size_t)4 * NROWS * 80 * 4;    //  2.6 MB
    float* opart = (float*)ob;  ob += (size_t)4 * NROWS * D_MODEL * 4; // 25.2 MB

    // ---- call-static preprocessing (weights, embedding) ----
    cvt_bf16_kernel<<<VOCAB * D_MODEL / 8 / 256, 256, 0, stream>>>(
        emb, emb_bf, VOCAB * D_MODEL);
    cvt_layer_weights<<<2 * 3760128 / 256, 256, 0, stream>>>(
        ipw, xpw, dtw, opw, wip, wxp, wdt, wop);
    embed_kernel<<<NROWS, 192, 0, stream>>>(ids, emb, x);
    rmsnorm_kernel<<<NROWS, 256, 0, stream>>>(x, norm_w, xn);

    for (int l = 0; l < 2; ++l) {
        // in_proj: (2048x768)(3072x768)^T -> xr
        gemm_bt<0><<<16 * 24, 256, 0, stream>>>(
            xn, wip + (size_t)l * 3072 * 768, xr, nullptr,
            NROWS, 3072, D_MODEL, D_MODEL, 16);
        conv_silu_kernel<<<NROWS * D_INNER / 256, 256, 0, stream>>>(
            xr, cw + (size_t)l * D_INNER * 4, cb + (size_t)l * D_INNER, uf, ub);
        // x_proj: (2048x1536)(80x1536)^T, split-K x4 -> partials
        gemm_bt<0><<<dim3(16, 4), 256, 0, stream>>>(
            ub, wxp + (size_t)l * 80 * 1536, xpart, nullptr,
            NROWS, 80, 384, D_INNER, 16);
        reduce_xp_kernel<<<NROWS * 80 / 256, 256, 0, stream>>>(
            xpart, xdbl, dtraw);                         // + fused pad_dt
        // dt_proj + softplus: (2048x64)(1536x64)^T -> delta
        gemm_bt<2><<<16 * 12, 256, 0, stream>>>(
            dtraw, wdt + (size_t)l * 1536 * 64, delta,
            dtb + (size_t)l * D_INNER, NROWS, D_INNER, 64, 64, 16);
        // chunked selective scan
        scan_pass1<<<dim3(192, NCHUNK), 256, 0, stream>>>(
            delta, uf, xdbl, alog + (size_t)l * D_INNER * D_STATE, Pbuf, Hbuf);
        scan_pass2<<<CHST / 256, 256, 0, stream>>>(Pbuf, Hbuf, Hin);
        scan_pass3<<<dim3(192, NCHUNK), 256, 0, stream>>>(
            delta, uf, xdbl, xr, alog + (size_t)l * D_INNER * D_STATE,
            Dp + (size_t)l * D_INNER, Hin, yb);
        // out_proj: (2048x1536)(768x1536)^T, split-K x4 -> partials
        gemm_bt<0><<<dim3(96, 4), 256, 0, stream>>>(
            yb, wop + (size_t)l * 768 * 1536, opart, nullptr,
            NROWS, D_MODEL, 384, D_INNER, 16);
        // reduce + residual into x + rmsnorm for next stage
        reduce_res_norm_kernel<<<NROWS, 256, 0, stream>>>(
            opart, x, (l == 0) ? (norm_w + D_MODEL) : nfw, xn);
    }

    // logits: (2048x768)(32000x768)^T -> out  [256^2 8-phase kernel, 1000 blocks]
    gemm256<<<8 * 125, 512, 0, stream>>>(xn, emb_bf, out,
                                         NROWS, VOCAB, D_MODEL, 8);
}